// Round 2
// baseline (449.409 us; speedup 1.0000x reference)
//
#include <hip/hip_runtime.h>

// Native clang vector type so __builtin_nontemporal_{load,store} lower to
// single global_load/store_dwordx4 with the nt cache hint.
typedef float f4 __attribute__((ext_vector_type(4)));

// Mask scratch in a device global (d_ws poison fills proved unconditional,
// but the global costs nothing and keeps d_ws out of the picture).
#define MAXD 16384
__device__ f4 g_mask4[MAXD / 4];   // 64 KB capacity; D=4096 uses 16 KB

// -------------------------------------------------------------------------
// Kernel 1: top-k channel mask from importance.
// jax.lax.top_k keeps the `keep` largest, ties broken toward lower index.
// Element i kept iff rank(i) < keep, where
//   rank(i) = #{j : imp[j] > imp[i]} + #{j < i : imp[j] == imp[i]}
// One block (1 wave, 64 lanes) per channel; importance (16 KB) is L1/L2-hot.
// Total traffic D*D*4B = 64 MB of L2-hot reads ≈ 2 µs — not the lever.
// -------------------------------------------------------------------------
__global__ __launch_bounds__(64) void topk_mask_kernel(
    const float* __restrict__ imp, int D, int keep)
{
    const int i = blockIdx.x;
    const float vi = imp[i];
    int cnt = 0;
    for (int j = (int)threadIdx.x; j < D; j += 64) {
        const float vj = imp[j];
        cnt += (vj > vi) || (vj == vi && j < i);
    }
    // wave-64 butterfly reduce
    #pragma unroll
    for (int off = 32; off > 0; off >>= 1)
        cnt += __shfl_down(cnt, off, 64);
    if (threadIdx.x == 0)
        ((float*)g_mask4)[i] = (cnt < keep) ? 1.0f : 0.0f;
}

// -------------------------------------------------------------------------
// Kernel 2: elementwise sparse polynomial, grid-stride.
// y[d in mask]  = c0*x + c1*x^2 + c2*x^3   (Horner)
// y[d !in mask] = x
// 2048 blocks x 256 threads, ~32 float4/thread (G11: cap grid, stride rest).
// Key trick: stride (blocks*256) is a multiple of the mask period D/4, so
// each thread's mask float4 is LOOP-INVARIANT -> load once, keep in VGPRs.
// The inner loop is then a pure x-load / 6 fma / out-store stream with nt
// cache hints (zero reuse; keeps L2 for the mask + harness).
// -------------------------------------------------------------------------
__global__ __launch_bounds__(256) void sparse_poly_kernel(
    const f4* __restrict__ x, const float* __restrict__ coeffs,
    f4* __restrict__ out, int n4, int d4mask)
{
    const int tid    = blockIdx.x * 256 + (int)threadIdx.x;
    const int stride = gridDim.x * 256;

    const float c0 = coeffs[0];
    const float c1 = coeffs[1];
    const float c2 = coeffs[2];

    if ((stride & d4mask) == 0) {
        // stride is a multiple of the mask period: mask index invariant.
        const f4 m = g_mask4[tid & d4mask];
        #pragma unroll 4
        for (int idx = tid; idx < n4; idx += stride) {
            const f4 v = __builtin_nontemporal_load(&x[idx]);
            f4 r;
            r.x = (m.x != 0.0f) ? fmaf(fmaf(c2, v.x, c1), v.x, c0) * v.x : v.x;
            r.y = (m.y != 0.0f) ? fmaf(fmaf(c2, v.y, c1), v.y, c0) * v.y : v.y;
            r.z = (m.z != 0.0f) ? fmaf(fmaf(c2, v.z, c1), v.z, c0) * v.z : v.z;
            r.w = (m.w != 0.0f) ? fmaf(fmaf(c2, v.w, c1), v.w, c0) * v.w : v.w;
            __builtin_nontemporal_store(r, &out[idx]);
        }
    } else {
        // generic fallback (not hit for D=4096 with this grid)
        #pragma unroll 4
        for (int idx = tid; idx < n4; idx += stride) {
            const f4 m = g_mask4[idx & d4mask];
            const f4 v = __builtin_nontemporal_load(&x[idx]);
            f4 r;
            r.x = (m.x != 0.0f) ? fmaf(fmaf(c2, v.x, c1), v.x, c0) * v.x : v.x;
            r.y = (m.y != 0.0f) ? fmaf(fmaf(c2, v.y, c1), v.y, c0) * v.y : v.y;
            r.z = (m.z != 0.0f) ? fmaf(fmaf(c2, v.z, c1), v.z, c0) * v.z : v.z;
            r.w = (m.w != 0.0f) ? fmaf(fmaf(c2, v.w, c1), v.w, c0) * v.w : v.w;
            __builtin_nontemporal_store(r, &out[idx]);
        }
    }
}

extern "C" void kernel_launch(void* const* d_in, const int* in_sizes, int n_in,
                              void* d_out, int out_size, void* d_ws, size_t ws_size,
                              hipStream_t stream) {
    const float* x          = (const float*)d_in[0];   // (B,T,D) fp32
    const float* coeffs     = (const float*)d_in[1];   // (3,) fp32
    const float* importance = (const float*)d_in[2];   // (D,) fp32

    const int D    = in_sizes[2];          // 4096
    const int keep = D / 2;                // keep_ratio = 0.5 -> 2048
    const int n    = in_sizes[0];          // 67108864
    const int n4   = n / 4;

    (void)d_ws; (void)ws_size;             // intentionally unused

    // mask: one wave per channel
    topk_mask_kernel<<<D, 64, 0, stream>>>(importance, D, keep);

    // elementwise: capped grid + grid-stride (2048 blocks = 8 blocks/CU)
    int blocks = 2048;
    const int need = (n4 + 255) / 256;
    if (need < blocks) blocks = need;
    sparse_poly_kernel<<<blocks, 256, 0, stream>>>(
        (const f4*)x, coeffs, (f4*)d_out, n4, D / 4 - 1);
}

// Round 3
// 424.576 us; speedup vs baseline: 1.0585x; 1.0585x over previous
//
#include <hip/hip_runtime.h>

// Native clang vector type so __builtin_nontemporal_{load,store} lower to
// single global_load/store_dwordx4 with the nt cache hint.
typedef float f4 __attribute__((ext_vector_type(4)));

// Mask scratch in a device global (d_ws poison fills proved unconditional;
// the global costs nothing and keeps d_ws out of the picture).
#define MAXD 16384
__device__ f4 g_mask4[MAXD / 4];   // 64 KB capacity; D=4096 uses 16 KB

// -------------------------------------------------------------------------
// Kernel 1: top-k channel mask from importance.
// jax.lax.top_k keeps the `keep` largest, ties broken toward lower index.
// Element i kept iff rank(i) < keep, where
//   rank(i) = #{j : imp[j] > imp[i]} + #{j < i : imp[j] == imp[i]}
// One block (1 wave, 64 lanes) per channel; importance (16 KB) is L1/L2-hot.
// Total traffic D*D*4B = 64 MB of cache-hot reads ≈ 2-3 µs — not the lever.
// -------------------------------------------------------------------------
__global__ __launch_bounds__(64) void topk_mask_kernel(
    const float* __restrict__ imp, int D, int keep)
{
    const int i = blockIdx.x;
    const float vi = imp[i];
    int cnt = 0;
    for (int j = (int)threadIdx.x; j < D; j += 64) {
        const float vj = imp[j];
        cnt += (vj > vi) || (vj == vi && j < i);
    }
    // wave-64 butterfly reduce
    #pragma unroll
    for (int off = 32; off > 0; off >>= 1)
        cnt += __shfl_down(cnt, off, 64);
    if (threadIdx.x == 0)
        ((float*)g_mask4)[i] = (cnt < keep) ? 1.0f : 0.0f;
}

// -------------------------------------------------------------------------
// Kernel 2: elementwise sparse polynomial.
// y[d in mask]  = c0*x + c1*x^2 + c2*x^3   (Horner)
// y[d !in mask] = x
// One float4 per thread, one-shot 65536-block dispatch (R2 post-mortem:
// grid-stride at 2048 blocks REGRESSED +27%; the tiny-block one-shot sweep
// is the fastest measured structure for this stream). x/out have zero reuse
// -> nt hints; mask float4 vector (16 KB) stays L1/L2-hot via cached loads.
// -------------------------------------------------------------------------
__global__ __launch_bounds__(256) void sparse_poly_kernel(
    const f4* __restrict__ x, const float* __restrict__ coeffs,
    f4* __restrict__ out, int n4, int d4mask)
{
    const int idx = blockIdx.x * 256 + (int)threadIdx.x;
    if (idx >= n4) return;

    const float c0 = coeffs[0];
    const float c1 = coeffs[1];
    const float c2 = coeffs[2];

    const f4 m = g_mask4[idx & d4mask];
    const f4 v = __builtin_nontemporal_load(&x[idx]);

    f4 r;
    r.x = (m.x != 0.0f) ? fmaf(fmaf(c2, v.x, c1), v.x, c0) * v.x : v.x;
    r.y = (m.y != 0.0f) ? fmaf(fmaf(c2, v.y, c1), v.y, c0) * v.y : v.y;
    r.z = (m.z != 0.0f) ? fmaf(fmaf(c2, v.z, c1), v.z, c0) * v.z : v.z;
    r.w = (m.w != 0.0f) ? fmaf(fmaf(c2, v.w, c1), v.w, c0) * v.w : v.w;

    __builtin_nontemporal_store(r, &out[idx]);
}

extern "C" void kernel_launch(void* const* d_in, const int* in_sizes, int n_in,
                              void* d_out, int out_size, void* d_ws, size_t ws_size,
                              hipStream_t stream) {
    const float* x          = (const float*)d_in[0];   // (B,T,D) fp32
    const float* coeffs     = (const float*)d_in[1];   // (3,) fp32
    const float* importance = (const float*)d_in[2];   // (D,) fp32

    const int D    = in_sizes[2];          // 4096
    const int keep = D / 2;                // keep_ratio = 0.5 -> 2048
    const int n    = in_sizes[0];          // 67108864
    const int n4   = n / 4;

    (void)d_ws; (void)ws_size;             // intentionally unused

    // mask: one wave per channel
    topk_mask_kernel<<<D, 64, 0, stream>>>(importance, D, keep);

    // elementwise: one float4 per thread
    const int blocks = (n4 + 255) / 256;
    sparse_poly_kernel<<<blocks, 256, 0, stream>>>(
        (const f4*)x, coeffs, (f4*)d_out, n4, D / 4 - 1);
}